// Round 1
// 452.829 us; speedup vs baseline: 1.2111x; 1.2111x over previous
//
#include <hip/hip_runtime.h>
#include <hip/hip_bf16.h>

typedef unsigned short u16;
typedef __bf16 bf16x8 __attribute__((ext_vector_type(8)));
typedef float  f32x4  __attribute__((ext_vector_type(4)));

#define N_  16384
#define SCALE_ 0.125f
#define TILE 128
#define TPAD 66
#define APAD 264   // atb row stride (u16): 528B, 16B-aligned, 2-way-max banks

__device__ __forceinline__ u16 f2b(float f){
  unsigned u = __float_as_uint(f);
  unsigned r = (u + 0x7fffu + ((u>>16)&1u)) >> 16;
  return (u16)r;
}
__device__ __forceinline__ float blo(unsigned u){ return __uint_as_float(u<<16); }
__device__ __forceinline__ float bhi(unsigned u){ return __uint_as_float(u & 0xffff0000u); }
__device__ __forceinline__ float b2f(u16 v){ return __uint_as_float(((unsigned)v)<<16); }
__device__ __forceinline__ void ld8(const float* __restrict__ p, float* f){
  const float4 a = ((const float4*)p)[0];
  const float4 b = ((const float4*)p)[1];
  f[0]=a.x; f[1]=a.y; f[2]=a.z; f[3]=a.w;
  f[4]=b.x; f[5]=b.y; f[6]=b.z; f[7]=b.w;
}
__device__ __forceinline__ bf16x8 frag8(const float* __restrict__ p){
  float f[8]; ld8(p, f);
  bf16x8 r;
  #pragma unroll
  for (int j=0;j<8;++j) r[j] = (__bf16)f[j];
  return r;
}
__device__ __forceinline__ void unpk4u(uint4 u, float* f){
  f[0]=blo(u.x); f[1]=bhi(u.x);
  f[2]=blo(u.y); f[3]=bhi(u.y);
  f[4]=blo(u.z); f[5]=bhi(u.z);
  f[6]=blo(u.w); f[7]=bhi(u.w);
}

// ---------------- diagnostic marker (fp32 out) ----------------
__global__ __launch_bounds__(256) void k_marker(float* __restrict__ out, int n, float val){
  const int i = blockIdx.x*256 + threadIdx.x;
  if (i < n) out[i] = val;
}

// ---------------- slots init: mu + sigma * noise ----------------
__global__ __launch_bounds__(256) void k_init_slots(
  const float* __restrict__ mu, const float* __restrict__ sigma,
  const float* __restrict__ noise, float* __restrict__ slots)
{
  const int idx = blockIdx.x*256 + threadIdx.x;   // grid 56*256 = 14336 exact
  const int d = idx & 63;
  slots[idx] = mu[d] + sigma[d] * noise[idx];
}

// ---------------- Wk transpose: wkT[e][d] = Wk[d][e] (once) ----------------
__global__ __launch_bounds__(256) void k_wkt(const float* __restrict__ Wk, float* __restrict__ wkT){
  const int i = blockIdx.x*256 + threadIdx.x;     // grid 16*256 = 4096 exact
  const int e = i>>6, d = i&63;
  wkT[i] = Wk[d*64 + e];
}

// ---------------- xln: LayerNorm(inputs) -> bf16, row-major ----------------
// grid 2048 x 256. Each 16-lane group holds one full row per pass (fully
// coalesced 16B/lane reads, 8B/lane writes). In-group shuffle LN reduce.
__global__ __launch_bounds__(256) void k_xln(
  const float* __restrict__ x, const float* __restrict__ g_in, const float* __restrict__ b_in,
  u16* __restrict__ xout)
{
  const int t = threadIdx.x;
  const long blk = blockIdx.x;
  const float4 gv = *(const float4*)(g_in + (t&15)*4);
  const float4 bb = *(const float4*)(b_in + (t&15)*4);
  const float* xbase = x + blk*16384;       // 256 rows * 64 f
  u16* obase = xout + blk*16384;
  float4 v[16];
  #pragma unroll
  for (int p=0;p<16;++p) v[p] = *(const float4*)(xbase + p*1024 + t*4);
  #pragma unroll
  for (int p=0;p<16;++p){
    float s = v[p].x + v[p].y + v[p].z + v[p].w;
    float q = v[p].x*v[p].x + v[p].y*v[p].y + v[p].z*v[p].z + v[p].w*v[p].w;
    #pragma unroll
    for (int off=1; off<16; off<<=1){ s += __shfl_xor(s, off); q += __shfl_xor(q, off); }
    const float mean = s*(1.f/64.f);
    const float rstd = rsqrtf(q*(1.f/64.f) - mean*mean + 1e-5f);
    const u16 e0 = f2b((v[p].x-mean)*rstd*gv.x + bb.x);
    const u16 e1 = f2b((v[p].y-mean)*rstd*gv.y + bb.y);
    const u16 e2 = f2b((v[p].z-mean)*rstd*gv.z + bb.z);
    const u16 e3 = f2b((v[p].w-mean)*rstd*gv.w + bb.w);
    const unsigned w0 = (unsigned)e0 | ((unsigned)e1<<16);
    const unsigned w1 = (unsigned)e2 | ((unsigned)e3<<16);
    *(uint2*)(obase + p*1024 + t*4) = make_uint2(w0, w1);
  }
}

// ---------------- per-iter: q = ln(slots)@Wq^T + bq; qk = q@Wk; qb = q.bk ----
__global__ __launch_bounds__(256) void k_qln_zero(
  const float* __restrict__ slots, const float* __restrict__ Wq, const float* __restrict__ bq,
  const float* __restrict__ g_sl, const float* __restrict__ b_sl,
  const float* __restrict__ wkT, const float* __restrict__ bk,
  float* __restrict__ qout, float* __restrict__ qkb, float* __restrict__ qbb,
  float* __restrict__ num, float* __restrict__ den, const int do_qk)
{
  const int tid = blockIdx.x*256 + threadIdx.x;    // grid 56*256 = 14336 exact
  num[tid] = 0.f;
  if (tid < 224) den[tid] = 0.f;
  const int ri = tid >> 6, lane = tid & 63;
  const float xv = slots[ri*64 + lane];
  float s = xv, ss = xv*xv;
  #pragma unroll
  for (int off=1; off<64; off<<=1){ s += __shfl_xor(s,off); ss += __shfl_xor(ss,off); }
  const float mean = s*(1.f/64.f);
  const float rstd = rsqrtf(ss*(1.f/64.f) - mean*mean + 1e-5f);
  const float sn = (xv-mean)*rstd*g_sl[lane] + b_sl[lane];
  float acc = 0.f;
  for (int d8=0; d8<8; ++d8){
    float wf[8]; ld8(Wq + lane*64 + d8*8, wf);
    #pragma unroll
    for (int j=0;j<8;++j) acc += __shfl(sn, d8*8+j) * wf[j];
  }
  const float qv = acc + bq[lane];
  qout[ri*64+lane] = qv;
  if (do_qk){
    float pb = qv * bk[lane];
    #pragma unroll
    for (int off=1; off<64; off<<=1) pb += __shfl_xor(pb, off);
    if (lane == 0) qbb[ri] = pb;
    float qkv = 0.f;
    for (int d8=0; d8<8; ++d8){
      float wf[8]; ld8(wkT + lane*64 + d8*8, wf);
      #pragma unroll
      for (int j=0;j<8;++j) qkv += __shfl(qv, d8*8+j) * wf[j];
    }
    qkb[ri*64+lane] = qkv;
  }
}

// ================= FAST PATH: streaming attention on xln only =================
// dots_ij = qk_i . xln_j + qb_i  (no K buffer); acc_i = sum_j a_ij xln_j via MFMA
// (Wv^T + bv applied later in k_gru_mlp). grid = 32 b x 32 ch (512 keys/block).
// xs: 256x64 bf16 tile, XOR-swizzled (byte ^= (key&7)<<4) -> conflict-free rows.
__global__ __launch_bounds__(256) void k_attn3(
  const u16* __restrict__ xln, const float* __restrict__ qkb, const float* __restrict__ qbb,
  float* __restrict__ num, float* __restrict__ den)
{
  __shared__ __align__(16) u16   xs[256*64];     // 32 KB swizzled x̂ tile
  __shared__ __align__(16) u16   atb[7*APAD];    // bf16 attn weights
  __shared__ __align__(16) float qs[448];
  __shared__ float qbs[7];
  __shared__ float den_s[7];
  const int t = threadIdx.x;
  const int b = blockIdx.x >> 5, ch = blockIdx.x & 31;
  for (int i=t;i<448;i+=256) qs[i] = qkb[b*448+i];
  if (t<7){ qbs[t] = qbb[b*7+t]; den_s[t] = 0.f; }
  const int wid = t>>6, lane = t&63;
  const u16* gbase = xln + ((long)b*N_ + ch*512)*64;
  uint4 st[8];
  f32x4 accv = {0.f,0.f,0.f,0.f};

  // ---- stage tile0 (reg -> swizzled LDS) ----
  #pragma unroll
  for (int p=0;p<8;++p) st[p] = *(const uint4*)(gbase + p*2048 + t*8);
  #pragma unroll
  for (int p=0;p<8;++p)
    *(uint4*)&xs[(p*32 + (t>>3))*64 + (((t&7) ^ ((t>>3)&7))<<3)] = st[p];
  __syncthreads();
  // T14: issue tile1 loads now; written to LDS after phase B0.
  #pragma unroll
  for (int p=0;p<8;++p) st[p] = *(const uint4*)(gbase + 16384 + p*2048 + t*8);

  auto phaseA = [&](){
    // thread t owns key t of the tile
    float acc[7];
    #pragma unroll
    for (int i=0;i<7;++i) acc[i]=0.f;
    #pragma unroll
    for (int seg=0; seg<8; ++seg){
      const uint4 kw = *(const uint4*)&xs[t*64 + ((seg ^ (t&7))<<3)];
      float kf[8]; unpk4u(kw, kf);
      #pragma unroll
      for (int i=0;i<7;++i){
        const float4 qa = *(const float4*)&qs[i*64 + seg*8];
        const float4 qb4 = *(const float4*)&qs[i*64 + seg*8 + 4];
        acc[i] += kf[0]*qa.x + kf[1]*qa.y + kf[2]*qa.z + kf[3]*qa.w
                + kf[4]*qb4.x + kf[5]*qb4.y + kf[6]*qb4.z + kf[7]*qb4.w;
      }
    }
    float mx = -1e30f;
    #pragma unroll
    for (int i=0;i<7;++i){ acc[i] = (acc[i] + qbs[i]) * SCALE_; mx = fmaxf(mx, acc[i]); }
    float e[7]; float sum = 0.f;
    #pragma unroll
    for (int i=0;i<7;++i){ e[i] = __expf(acc[i]-mx); sum += e[i]; }
    const float inv = 1.f/sum;
    float dsum[7];
    #pragma unroll
    for (int i=0;i<7;++i){
      const u16 rb = f2b(e[i]*inv + 1e-8f);
      atb[i*APAD + t] = rb;
      dsum[i] = b2f(rb);            // den from the SAME rounded weights as num
    }
    #pragma unroll
    for (int i=0;i<7;++i){
      #pragma unroll
      for (int off=1; off<64; off<<=1) dsum[i] += __shfl_xor(dsum[i], off);
    }
    if (lane == 0){
      #pragma unroll
      for (int i=0;i<7;++i) atomicAdd(&den_s[i], dsum[i]);
    }
  };

  // phase B: acc^T[dim][slot] += x̂^T[dim][key] @ attn^T[key][slot] via MFMA.
  // Frag layouts derived from verified k_kv pattern:
  //   A: m=lane&15 (dim in 16-group), k=(lane>>4)*8+j (key)
  //   B: n=lane&15 (slot), k=(lane>>4)*8+j (key)
  //   C: col=lane&15 (slot), row=(lane>>4)*4+r (dim in group)
  const int m15 = lane & 15;
  const int kq = (lane>>4)<<3;
  const int dim2 = ((wid<<4) + m15) << 1;   // byte col of this lane's A-dim
  auto phaseB = [&](){
    #pragma unroll
    for (int ks=0; ks<8; ++ks){
      const int kbase = ks*32 + kq;         // kbase % 8 == 0 -> key&7 == j
      const unsigned a0 = xs[(kbase+0)*64 + ((dim2 ^ (0<<4))>>1)];
      const unsigned a1 = xs[(kbase+1)*64 + ((dim2 ^ (1<<4))>>1)];
      const unsigned a2 = xs[(kbase+2)*64 + ((dim2 ^ (2<<4))>>1)];
      const unsigned a3 = xs[(kbase+3)*64 + ((dim2 ^ (3<<4))>>1)];
      const unsigned a4 = xs[(kbase+4)*64 + ((dim2 ^ (4<<4))>>1)];
      const unsigned a5 = xs[(kbase+5)*64 + ((dim2 ^ (5<<4))>>1)];
      const unsigned a6 = xs[(kbase+6)*64 + ((dim2 ^ (6<<4))>>1)];
      const unsigned a7 = xs[(kbase+7)*64 + ((dim2 ^ (7<<4))>>1)];
      const uint4 aw = make_uint4(a0|(a1<<16), a2|(a3<<16), a4|(a5<<16), a6|(a7<<16));
      const bf16x8 af = __builtin_bit_cast(bf16x8, aw);
      uint4 bw = make_uint4(0u,0u,0u,0u);
      if (m15 < 7) bw = *(const uint4*)&atb[m15*APAD + kbase];
      const bf16x8 bfv = __builtin_bit_cast(bf16x8, bw);
      accv = __builtin_amdgcn_mfma_f32_16x16x32_bf16(af, bfv, accv, 0,0,0);
    }
  };

  phaseA();
  __syncthreads();          // atb + den ready
  phaseB();
  __syncthreads();          // xs free for tile1
  #pragma unroll
  for (int p=0;p<8;++p)
    *(uint4*)&xs[(p*32 + (t>>3))*64 + (((t&7) ^ ((t>>3)&7))<<3)] = st[p];
  __syncthreads();
  phaseA();
  __syncthreads();
  if (t < 7) atomicAdd(&den[b*7+t], den_s[t]);
  phaseB();

  if (m15 < 7){
    float* np = &num[((long)b*7 + m15)*64 + (wid<<4) + ((lane>>4)<<2)];
    #pragma unroll
    for (int r=0;r<4;++r) atomicAdd(np + r, accv[r]);
  }
}

// ================= FALLBACK: fused attention (verified, round-6) =================
__global__ __launch_bounds__(256) void k_attn_fused(
  const float* __restrict__ x,
  const float* __restrict__ Wk, const float* __restrict__ bk,
  const float* __restrict__ Wv, const float* __restrict__ bv,
  const float* __restrict__ g_in, const float* __restrict__ b_in,
  const float* __restrict__ qbuf, float* __restrict__ num, float* __restrict__ den)
{
  __shared__ __align__(16) u16   tile[TILE*TPAD];
  __shared__ __align__(16) float qs[7*64];
  __shared__ __align__(16) float at[7*TILE];
  const int t = threadIdx.x;
  const int b = blockIdx.x >> 6, ch = blockIdx.x & 63;
  for (int i=t; i<448; i+=256) qs[i] = qbuf[b*448 + i];
  const int wid = t>>6, lane = t&63;
  const int m = lane & 15, q4 = lane >> 4;
  float gf[16], bfv[16];
  ld8(g_in + q4*8, gf);  ld8(g_in + 32 + q4*8, gf+8);
  ld8(b_in + q4*8, bfv); ld8(b_in + 32 + q4*8, bfv+8);
  const int i0 = wid*2, i1 = wid*2+1;
  float n0=0.f, n1=0.f, d0=0.f, d1=0.f;

  for (int tl=0; tl<2; ++tl){
    const long j0 = (long)ch*256 + tl*TILE;
    const long rowbase = (long)b*N_ + j0 + (long)wid*32;
    __syncthreads();
    bf16x8 af[2][2];
    #pragma unroll
    for (int rg=0; rg<2; ++rg){
      const float* xr = x + (rowbase + rg*16 + m)*64;
      float xf[16];
      ld8(xr + q4*8, xf); ld8(xr + 32 + q4*8, xf+8);
      float s=0.f, ss=0.f;
      #pragma unroll
      for (int i=0;i<16;++i){ s += xf[i]; ss += xf[i]*xf[i]; }
      s  += __shfl_xor(s,16);  s  += __shfl_xor(s,32);
      ss += __shfl_xor(ss,16); ss += __shfl_xor(ss,32);
      const float mean = s*(1.f/64.f);
      const float rstd = rsqrtf(ss*(1.f/64.f) - mean*mean + 1e-5f);
      #pragma unroll
      for (int j=0;j<8;++j){
        af[rg][0][j] = (__bf16)((xf[j]  -mean)*rstd*gf[j]   + bfv[j]);
        af[rg][1][j] = (__bf16)((xf[8+j]-mean)*rstd*gf[8+j] + bfv[8+j]);
      }
    }
    {
      bf16x8 w0[4], w1[4]; float bc[4];
      #pragma unroll
      for (int cg=0; cg<4; ++cg){
        const int n = cg*16 + m;
        w0[cg] = frag8(Wk + n*64 + q4*8);
        w1[cg] = frag8(Wk + n*64 + 32 + q4*8);
        bc[cg] = bk[n];
      }
      #pragma unroll
      for (int rg=0; rg<2; ++rg){
        #pragma unroll
        for (int cg=0; cg<4; ++cg){
          f32x4 acc = {0.f,0.f,0.f,0.f};
          acc = __builtin_amdgcn_mfma_f32_16x16x32_bf16(af[rg][0], w0[cg], acc, 0,0,0);
          acc = __builtin_amdgcn_mfma_f32_16x16x32_bf16(af[rg][1], w1[cg], acc, 0,0,0);
          const int col = cg*16 + m;
          #pragma unroll
          for (int r=0;r<4;++r)
            tile[(wid*32 + rg*16 + q4*4 + r)*TPAD + col] = f2b(acc[r] + bc[cg]);
        }
      }
    }
    __syncthreads();
    if (t < TILE){
      float acc[7];
      #pragma unroll
      for (int i=0;i<7;++i) acc[i]=0.f;
      const unsigned* krow = (const unsigned*)&tile[t*TPAD];
      for (int wq=0; wq<8; ++wq){
        const unsigned k0 = krow[wq*4+0], k1 = krow[wq*4+1], k2 = krow[wq*4+2], k3 = krow[wq*4+3];
        float kf[8];
        kf[0]=blo(k0); kf[1]=bhi(k0); kf[2]=blo(k1); kf[3]=bhi(k1);
        kf[4]=blo(k2); kf[5]=bhi(k2); kf[6]=blo(k3); kf[7]=bhi(k3);
        #pragma unroll
        for (int i=0;i<7;++i){
          const float4 qa = *(const float4*)&qs[i*64 + wq*8];
          const float4 qb = *(const float4*)&qs[i*64 + wq*8 + 4];
          acc[i] += kf[0]*qa.x + kf[1]*qa.y + kf[2]*qa.z + kf[3]*qa.w
                  + kf[4]*qb.x + kf[5]*qb.y + kf[6]*qb.z + kf[7]*qb.w;
        }
      }
      float mx = -1e30f;
      #pragma unroll
      for (int i=0;i<7;++i){ acc[i] *= SCALE_; mx = fmaxf(mx, acc[i]); }
      float e[7]; float sum = 0.f;
      #pragma unroll
      for (int i=0;i<7;++i){ e[i] = __expf(acc[i]-mx); sum += e[i]; }
      const float inv = 1.f/sum;
      #pragma unroll
      for (int i=0;i<7;++i) at[i*TILE + t] = e[i]*inv + 1e-8f;
    }
    __syncthreads();
    {
      bf16x8 w0[4], w1[4]; float bc[4];
      #pragma unroll
      for (int cg=0; cg<4; ++cg){
        const int n = cg*16 + m;
        w0[cg] = frag8(Wv + n*64 + q4*8);
        w1[cg] = frag8(Wv + n*64 + 32 + q4*8);
        bc[cg] = bv[n];
      }
      #pragma unroll
      for (int rg=0; rg<2; ++rg){
        #pragma unroll
        for (int cg=0; cg<4; ++cg){
          f32x4 acc = {0.f,0.f,0.f,0.f};
          acc = __builtin_amdgcn_mfma_f32_16x16x32_bf16(af[rg][0], w0[cg], acc, 0,0,0);
          acc = __builtin_amdgcn_mfma_f32_16x16x32_bf16(af[rg][1], w1[cg], acc, 0,0,0);
          const int col = cg*16 + m;
          #pragma unroll
          for (int r=0;r<4;++r)
            tile[(wid*32 + rg*16 + q4*4 + r)*TPAD + col] = f2b(acc[r] + bc[cg]);
        }
      }
    }
    __syncthreads();
    #pragma unroll 4
    for (int j=0;j<TILE;++j){
      const unsigned vw = ((const unsigned*)&tile[j*TPAD])[lane>>1];
      const float vf = (lane&1) ? bhi(vw) : blo(vw);
      const float a0v = at[i0*TILE+j];
      n0 += a0v*vf; d0 += a0v;
      if (i1 < 7){ const float a1v = at[i1*TILE+j]; n1 += a1v*vf; d1 += a1v; }
    }
  }
  atomicAdd(&num[(b*7+i0)*64 + lane], n0);
  if (lane==0) atomicAdd(&den[b*7+i0], d0);
  if (i1 < 7){
    atomicAdd(&num[(b*7+i1)*64 + lane], n1);
    if (lane==0) atomicAdd(&den[b*7+i1], d1);
  }
}

// ---------------- per-iter: updates -> GRU -> residual MLP ----------------
// fastmode: num holds attn-weighted x̂ sums; apply u = (num/den)@Wv^T + bv here.
__global__ __launch_bounds__(256) void k_gru_mlp(
  const float* __restrict__ num, const float* __restrict__ den, float* __restrict__ slots,
  const float* __restrict__ Wv, const float* __restrict__ bv,
  const float* __restrict__ Wih, const float* __restrict__ Whh,
  const float* __restrict__ bih, const float* __restrict__ bhh,
  const float* __restrict__ mW1, const float* __restrict__ mb1,
  const float* __restrict__ mW2, const float* __restrict__ mb2,
  const float* __restrict__ g_ml, const float* __restrict__ b_ml,
  float* __restrict__ outp, const int write_out, const int fastmode)
{
  const int tid = blockIdx.x*256 + threadIdx.x;  // grid 56*256: 224 waves = 224 rows
  const int ri = tid>>6, lane = tid&63;
  const float dn = den[ri];
  const float a = (dn > 0.f) ? (num[ri*64+lane] / dn) : 0.f;
  float u;
  if (fastmode){
    float acc = 0.f;
    for (int e8=0; e8<8; ++e8){
      float f[8]; ld8(Wv + lane*64 + e8*8, f);
      #pragma unroll
      for (int j=0;j<8;++j) acc += __shfl(a, e8*8+j) * f[j];
    }
    u = acc + bv[lane];
  } else {
    u = a;
  }
  const float h = slots[ri*64+lane];
  float air=0,aiz=0,ain=0,ahr=0,ahz=0,ahn=0;
  for (int d8=0; d8<8; ++d8){
    float fir[8],fiz[8],fin[8],fhr[8],fhz[8],fhn[8];
    ld8(Wih + (      lane)*64 + d8*8, fir);
    ld8(Wih + ( 64 + lane)*64 + d8*8, fiz);
    ld8(Wih + (128 + lane)*64 + d8*8, fin);
    ld8(Whh + (      lane)*64 + d8*8, fhr);
    ld8(Whh + ( 64 + lane)*64 + d8*8, fhz);
    ld8(Whh + (128 + lane)*64 + d8*8, fhn);
    #pragma unroll
    for (int j=0;j<8;++j){
      const float ud = __shfl(u, d8*8+j);
      const float hd = __shfl(h, d8*8+j);
      air += ud*fir[j]; aiz += ud*fiz[j]; ain += ud*fin[j];
      ahr += hd*fhr[j]; ahz += hd*fhz[j]; ahn += hd*fhn[j];
    }
  }
  air += bih[lane]; aiz += bih[64+lane]; ain += bih[128+lane];
  ahr += bhh[lane]; ahz += bhh[64+lane]; ahn += bhh[128+lane];
  const float r = 1.f/(1.f + __expf(-(air+ahr)));
  const float z = 1.f/(1.f + __expf(-(aiz+ahz)));
  const float n = tanhf(ain + r*ahn);
  const float sv = (1.f-z)*n + z*h;
  float s=sv, ss=sv*sv;
  #pragma unroll
  for (int off=1; off<64; off<<=1){ s += __shfl_xor(s,off); ss += __shfl_xor(ss,off); }
  const float mean = s*(1.f/64.f);
  const float rstd = rsqrtf(ss*(1.f/64.f) - mean*mean + 1e-5f);
  const float m = (sv-mean)*rstd*g_ml[lane] + b_ml[lane];
  float h1a=0.f, h1b=0.f;
  for (int d8=0; d8<8; ++d8){
    float f1[8], f2[8];
    ld8(mW1 + (     lane)*64 + d8*8, f1);
    ld8(mW1 + (64 + lane)*64 + d8*8, f2);
    #pragma unroll
    for (int j=0;j<8;++j){
      const float md = __shfl(m, d8*8+j);
      h1a += md*f1[j]; h1b += md*f2[j];
    }
  }
  h1a = fmaxf(h1a + mb1[lane], 0.f);
  h1b = fmaxf(h1b + mb1[64+lane], 0.f);
  float o = 0.f;
  for (int h8=0; h8<8; ++h8){
    float fa[8], fb[8];
    ld8(mW2 + lane*128 + h8*8, fa);
    ld8(mW2 + lane*128 + 64 + h8*8, fb);
    #pragma unroll
    for (int j=0;j<8;++j){
      o += __shfl(h1a, h8*8+j)*fa[j] + __shfl(h1b, h8*8+j)*fb[j];
    }
  }
  o += mb2[lane];
  const float res = sv + o;
  slots[ri*64+lane] = res;
  if (write_out) outp[ri*64+lane] = res;
}

extern "C" void kernel_launch(void* const* d_in, const int* in_sizes, int n_in,
                              void* d_out, int out_size, void* d_ws, size_t ws_size,
                              hipStream_t stream)
{
  float* outp = (float*)d_out;
  static const int EXP[24] = {33554432,14336,64,64, 4096,64, 4096,64, 4096,64,
                              12288,12288,192,192, 8192,128, 8192,64,
                              64,64, 64,64, 64,64};
  if (n_in != 24){ k_marker<<<56,256,0,stream>>>(outp, out_size, 30.f); return; }
  for (int i=0;i<24;++i)
    if (in_sizes[i] != EXP[i]){ k_marker<<<56,256,0,stream>>>(outp, out_size, 40.f+(float)i); return; }
  if (out_size != 14336){ k_marker<<<56,256,0,stream>>>(outp, out_size, 33.f); return; }
  if (ws_size < 200000){ k_marker<<<56,256,0,stream>>>(outp, out_size, 35.f); return; }

  const float* inputs = (const float*)d_in[0];
  const float* noise  = (const float*)d_in[1];
  const float* mu     = (const float*)d_in[2];
  const float* sigma  = (const float*)d_in[3];
  const float* Wq  = (const float*)d_in[4];  const float* bq  = (const float*)d_in[5];
  const float* Wk  = (const float*)d_in[6];  const float* bk  = (const float*)d_in[7];
  const float* Wv  = (const float*)d_in[8];  const float* bv  = (const float*)d_in[9];
  const float* Wih = (const float*)d_in[10]; const float* Whh = (const float*)d_in[11];
  const float* bih = (const float*)d_in[12]; const float* bhh = (const float*)d_in[13];
  const float* mW1 = (const float*)d_in[14]; const float* mb1 = (const float*)d_in[15];
  const float* mW2 = (const float*)d_in[16]; const float* mb2 = (const float*)d_in[17];
  const float* g_in = (const float*)d_in[18]; const float* b_in = (const float*)d_in[19];
  const float* g_sl = (const float*)d_in[20]; const float* b_sl = (const float*)d_in[21];
  const float* g_ml = (const float*)d_in[22]; const float* b_ml = (const float*)d_in[23];

  char* ws = (char*)d_ws;
  float* slots = (float*)ws;                         // 14336 f
  float* qbuf  = (float*)(ws + 57344);               // 14336 f (plain q, fallback)
  float* qkb   = (float*)(ws + 114688);              // 14336 f (q @ Wk)
  float* num   = (float*)(ws + 172032);              // 14336 f
  float* den   = (float*)(ws + 229376);              // 224 f
  float* qbb   = (float*)(ws + 230272);              // 224 f (q . bk)
  float* wkT   = (float*)(ws + 231168);              // 4096 f (Wk^T)
  u16* xln     = (u16*)(ws + 247808);                // 33.5M bf16 (67.1 MB)
  const bool fast = (ws_size >= (size_t)247808 + 67108864ull);

  k_init_slots<<<56,256,0,stream>>>(mu, sigma, noise, slots);
  if (fast){
    k_wkt<<<16,256,0,stream>>>(Wk, wkT);
    k_xln<<<2048,256,0,stream>>>(inputs, g_in, b_in, xln);
  }
  for (int it=0; it<3; ++it){
    k_qln_zero<<<56,256,0,stream>>>(slots, Wq, bq, g_sl, b_sl, wkT, bk,
                                    qbuf, qkb, qbb, num, den, fast ? 1 : 0);
    if (fast)
      k_attn3<<<1024,256,0,stream>>>(xln, qkb, qbb, num, den);
    else
      k_attn_fused<<<2048,256,0,stream>>>(inputs, Wk, bk, Wv, bv, g_in, b_in, qbuf, num, den);
    k_gru_mlp<<<56,256,0,stream>>>(num, den, slots, Wv, bv, Wih, Whh, bih, bhh,
                                   mW1, mb1, mW2, mb2, g_ml, b_ml,
                                   outp, it==2 ? 1 : 0, fast ? 1 : 0);
  }
}